// Round 1
// baseline (578.504 us; speedup 1.0000x reference)
//
#include <hip/hip_runtime.h>
#include <hip/hip_bf16.h>
#include <math.h>

// ExpertChoiceMoELayer: B=8,S=2048,D=1024,F=2048,E=8 -> T=16384, cap=2048
#define T_TOK 16384
#define DIM   1024
#define FF    2048
#define NE    8
#define CAPK  2048

typedef unsigned short u16;
typedef __attribute__((ext_vector_type(8))) short bf16x8;
typedef __attribute__((ext_vector_type(4))) float f32x4;

__device__ __forceinline__ u16 f2bf(float f) {
  __hip_bfloat16 h = __float2bfloat16(f);
  union { __hip_bfloat16 h; u16 u; } c; c.h = h; return c.u;
}

__device__ __forceinline__ void async_copy16(const void* g, void* l) {
  __builtin_amdgcn_global_load_lds(
      (const __attribute__((address_space(1))) unsigned int*)g,
      (__attribute__((address_space(3))) unsigned int*)l, 16, 0, 0);
}

// ---- fp32 [E][R][C] -> bf16 [E][C][R] (B^T layout for MFMA GEMMs) ----
__global__ __launch_bounds__(256) void transpose_cvt(const float* __restrict__ src,
                                                     u16* __restrict__ dst, int R, int C) {
  __shared__ float tile[32][33];
  int e = blockIdx.z;
  int c0 = blockIdx.x * 32, r0 = blockIdx.y * 32;
  const float* s = src + (size_t)e * R * C;
  u16* d = dst + (size_t)e * R * C;
  int tx = threadIdx.x, ty = threadIdx.y; // 32 x 8
#pragma unroll
  for (int i = 0; i < 4; ++i) {
    int r = r0 + ty + i * 8;
    tile[ty + i * 8][tx] = s[(size_t)r * C + c0 + tx];
  }
  __syncthreads();
#pragma unroll
  for (int i = 0; i < 4; ++i) {
    int c = c0 + ty + i * 8;
    d[(size_t)c * R + r0 + tx] = f2bf(tile[tx][ty + i * 8]);
  }
}

// ---- router: logits (fp64 accum) + softmax; also emits xb (bf16 copy of x) ----
__global__ __launch_bounds__(256) void router_k(const float* __restrict__ x,
                                                const float* __restrict__ Wg,
                                                float* __restrict__ probs,
                                                u16* __restrict__ xb) {
  __shared__ float wg_s[DIM * NE]; // 32 KB
  int tid = threadIdx.x;
  for (int i = tid; i < DIM * NE; i += 256) wg_s[i] = Wg[i];
  __syncthreads();
  int wid = tid >> 6, lane = tid & 63;
  int t = blockIdx.x * 4 + wid;
  const float* xr = x + (size_t)t * DIM;
  u16* xbr = xb + (size_t)t * DIM;
  double acc[NE] = {0, 0, 0, 0, 0, 0, 0, 0};
#pragma unroll 1
  for (int it = 0; it < DIM / 64; ++it) {
    int d = it * 64 + lane;
    float xv = xr[d];
    xbr[d] = f2bf(xv);
    const float4* wrow = (const float4*)&wg_s[d * NE];
    float4 w0 = wrow[0], w1 = wrow[1];
    acc[0] += (double)xv * (double)w0.x;
    acc[1] += (double)xv * (double)w0.y;
    acc[2] += (double)xv * (double)w0.z;
    acc[3] += (double)xv * (double)w0.w;
    acc[4] += (double)xv * (double)w1.x;
    acc[5] += (double)xv * (double)w1.y;
    acc[6] += (double)xv * (double)w1.z;
    acc[7] += (double)xv * (double)w1.w;
  }
#pragma unroll
  for (int e = 0; e < NE; ++e)
    for (int o = 32; o > 0; o >>= 1) acc[e] += __shfl_down(acc[e], o, 64);
  if (lane == 0) {
    float l[NE], mx = -3.0e38f;
#pragma unroll
    for (int e = 0; e < NE; ++e) { l[e] = (float)acc[e]; mx = fmaxf(mx, l[e]); }
    float s = 0.f;
#pragma unroll
    for (int e = 0; e < NE; ++e) { l[e] = expf(l[e] - mx); s += l[e]; }
    float inv = 1.0f / s;
#pragma unroll
    for (int e = 0; e < NE; ++e) probs[(size_t)t * NE + e] = l[e] * inv;
  }
}

// ---- per-expert exact top-CAPK selection (radix select + index-ordered ties) ----
__global__ __launch_bounds__(256) void topk_sel(const float* __restrict__ probs,
                                                unsigned char* __restrict__ sel) {
  __shared__ unsigned int hist[256];
  __shared__ unsigned int bcast[2];
  __shared__ int tcnt[256];
  int e = blockIdx.x, tid = threadIdx.x;
  unsigned prefix = 0, remaining = CAPK;
#pragma unroll 1
  for (int level = 0; level < 4; ++level) {
    int shift = 24 - 8 * level;
    hist[tid] = 0;
    __syncthreads();
    for (int i = tid; i < T_TOK; i += 256) {
      unsigned k = __float_as_uint(probs[(size_t)i * NE + e]);
      if (level == 0 || (k >> (shift + 8)) == prefix)
        atomicAdd(&hist[(k >> shift) & 255u], 1u);
    }
    __syncthreads();
    if (tid == 0) {
      unsigned cum = 0;
      for (int b = 255; b >= 0; --b) {
        cum += hist[b];
        if (cum >= remaining) {
          bcast[0] = (unsigned)b;
          bcast[1] = remaining - (cum - hist[b]);
          break;
        }
      }
    }
    __syncthreads();
    prefix = (prefix << 8) | bcast[0];
    remaining = bcast[1];
    __syncthreads();
  }
  unsigned vk = prefix;
  int need = (int)remaining;
  const int CH = T_TOK / 256; // 64 tokens per thread, contiguous
  int i0 = tid * CH;
  int myt = 0;
  for (int i = i0; i < i0 + CH; ++i)
    myt += (__float_as_uint(probs[(size_t)i * NE + e]) == vk);
  tcnt[tid] = myt;
  __syncthreads();
  if (tid == 0) {
    int r = 0;
    for (int j = 0; j < 256; ++j) { int v = tcnt[j]; tcnt[j] = r; r += v; }
  }
  __syncthreads();
  int run = tcnt[tid];
  for (int i = i0; i < i0 + CH; ++i) {
    unsigned k = __float_as_uint(probs[(size_t)i * NE + e]);
    unsigned char s = 0;
    if (k > vk) s = 1;
    else if (k == vk) { if (run < need) s = 1; run++; }
    sel[(size_t)e * T_TOK + i] = s;
  }
}

__global__ void init_k(int* cnt, int* cnt2) {
  int i = threadIdx.x;
  if (i < NE) { cnt[i] = 0; cnt2[i] = 0; }
}

// conflict resolution: selected -> max-prob selecting expert (ties lowest e);
// unselected -> argmax expert. weight = probs[t, e*].
__global__ __launch_bounds__(256) void assign_k(const float* __restrict__ probs,
                                                const unsigned char* __restrict__ sel,
                                                int* __restrict__ tok2exp,
                                                float* __restrict__ wgt, int* cnt) {
  int t = blockIdx.x * 256 + threadIdx.x;
  float p[NE];
#pragma unroll
  for (int e = 0; e < NE; ++e) p[e] = probs[(size_t)t * NE + e];
  int best = -1; float bp = -3.0e38f;
#pragma unroll
  for (int e = 0; e < NE; ++e)
    if (sel[(size_t)e * T_TOK + t] && p[e] > bp) { bp = p[e]; best = e; }
  if (best < 0) {
#pragma unroll
    for (int e = 0; e < NE; ++e)
      if (p[e] > bp) { bp = p[e]; best = e; }
  }
  tok2exp[t] = best;
  wgt[t] = bp;
  atomicAdd(&cnt[best], 1);
}

__global__ void prefix_k(const int* cnt, int* basep) {
  if (threadIdx.x == 0) {
    int r = 0;
    for (int e = 0; e < NE; ++e) { basep[e] = r; r += cnt[e]; }
  }
}

__global__ __launch_bounds__(256) void slot_k(const int* __restrict__ tok2exp,
                                              const int* __restrict__ basep,
                                              int* cnt2, int* __restrict__ list) {
  int t = blockIdx.x * 256 + threadIdx.x;
  int e = tok2exp[t];
  int s = basep[e] + atomicAdd(&cnt2[e], 1);
  list[s] = t;
}

// ---- grouped GEMM 1: H[slot,:] = GELU(x[token] @ W1[e]) ; A gathered, B^T=[F][D] ----
__global__ __launch_bounds__(256, 2) void ffn1_k(const u16* __restrict__ xb,
                                                 const u16* __restrict__ w1t,
                                                 u16* __restrict__ H,
                                                 const int* __restrict__ list,
                                                 const int* __restrict__ basep,
                                                 const int* __restrict__ cnt) {
  int e = blockIdx.z;
  int ce = cnt[e];
  int mt = blockIdx.y;
  if (mt * 128 >= ce) return;
  int nt = blockIdx.x;
  int be = basep[e];
  __shared__ u16 As[128 * 64];
  __shared__ u16 Bs[128 * 64];
  __shared__ int toks[128];
  int tid = threadIdx.x;
  if (tid < 128) {
    int r = mt * 128 + tid;
    toks[tid] = (r < ce) ? list[be + r] : list[be];
  }
  __syncthreads();
  int wid = tid >> 6, lane = tid & 63;
  int rgrp = tid >> 3, cg = tid & 7;
  const char* ag[4]; const char* bg[4]; char* la[4]; char* lb[4];
#pragma unroll
  for (int j = 0; j < 4; ++j) {
    int row = j * 32 + rgrp;
    ag[j] = (const char*)(xb + (size_t)toks[row] * DIM + cg * 8);
    bg[j] = (const char*)(w1t + ((size_t)e * FF + nt * 128 + row) * DIM + cg * 8);
    la[j] = (char*)As + j * 4096 + wid * 1024;
    lb[j] = (char*)Bs + j * 4096 + wid * 1024;
  }
  f32x4 acc[4][4];
#pragma unroll
  for (int m = 0; m < 4; ++m)
#pragma unroll
    for (int n = 0; n < 4; ++n) acc[m][n] = (f32x4){0.f, 0.f, 0.f, 0.f};
  int wm = wid >> 1, wn = wid & 1;
#pragma unroll 1
  for (int kt = 0; kt < DIM / 64; ++kt) {
    size_t ko = (size_t)kt * 128; // bytes (64 bf16)
#pragma unroll
    for (int j = 0; j < 4; ++j) {
      async_copy16(ag[j] + ko, la[j]);
      async_copy16(bg[j] + ko, lb[j]);
    }
    __syncthreads();
#pragma unroll
    for (int kk = 0; kk < 2; ++kk) {
      bf16x8 a[4], b[4];
#pragma unroll
      for (int m = 0; m < 4; ++m)
        a[m] = *(const bf16x8*)&As[(wm * 64 + m * 16 + (lane & 15)) * 64 + kk * 32 + (lane >> 4) * 8];
#pragma unroll
      for (int n = 0; n < 4; ++n)
        b[n] = *(const bf16x8*)&Bs[(wn * 64 + n * 16 + (lane & 15)) * 64 + kk * 32 + (lane >> 4) * 8];
#pragma unroll
      for (int m = 0; m < 4; ++m)
#pragma unroll
        for (int n = 0; n < 4; ++n)
          acc[m][n] = __builtin_amdgcn_mfma_f32_16x16x32_bf16(a[m], b[n], acc[m][n], 0, 0, 0);
    }
    __syncthreads();
  }
  int lc = lane & 15, lr = (lane >> 4) * 4;
#pragma unroll
  for (int m = 0; m < 4; ++m) {
#pragma unroll
    for (int n = 0; n < 4; ++n) {
      int col = nt * 128 + wn * 64 + n * 16 + lc;
#pragma unroll
      for (int i = 0; i < 4; ++i) {
        int trow = wm * 64 + m * 16 + lr + i;
        int grow = mt * 128 + trow;
        if (grow < ce) {
          float v = acc[m][n][i];
          float g = 0.5f * v * (1.0f + erff(v * 0.70710678118654752f));
          H[(size_t)(be + grow) * FF + col] = f2bf(g);
        }
      }
    }
  }
}

// ---- grouped GEMM 2: out[token,:] = w * (H[slot,:] @ W2[e]) ; B^T=[D][F] ----
__global__ __launch_bounds__(256, 2) void ffn2_k(const u16* __restrict__ H,
                                                 const u16* __restrict__ w2t,
                                                 float* __restrict__ out,
                                                 const int* __restrict__ list,
                                                 const float* __restrict__ wgt,
                                                 const int* __restrict__ basep,
                                                 const int* __restrict__ cnt) {
  int e = blockIdx.z;
  int ce = cnt[e];
  int mt = blockIdx.y;
  if (mt * 128 >= ce) return;
  int nt = blockIdx.x; // 0..7 over DIM
  int be = basep[e];
  __shared__ u16 As[128 * 64];
  __shared__ u16 Bs[128 * 64];
  __shared__ int toks[128];
  __shared__ float wsc[128];
  int tid = threadIdx.x;
  if (tid < 128) {
    int r = mt * 128 + tid;
    int tk = (r < ce) ? list[be + r] : list[be];
    toks[tid] = tk;
    wsc[tid] = wgt[tk];
  }
  __syncthreads();
  int wid = tid >> 6, lane = tid & 63;
  int rgrp = tid >> 3, cg = tid & 7;
  const char* ag[4]; const char* bg[4]; char* la[4]; char* lb[4];
#pragma unroll
  for (int j = 0; j < 4; ++j) {
    int tr = j * 32 + rgrp;
    int gr = mt * 128 + tr;
    int r2 = (gr < ce) ? gr : (ce - 1);
    ag[j] = (const char*)(H + (size_t)(be + r2) * FF + cg * 8);
    bg[j] = (const char*)(w2t + ((size_t)e * DIM + nt * 128 + tr) * FF + cg * 8);
    la[j] = (char*)As + j * 4096 + wid * 1024;
    lb[j] = (char*)Bs + j * 4096 + wid * 1024;
  }
  f32x4 acc[4][4];
#pragma unroll
  for (int m = 0; m < 4; ++m)
#pragma unroll
    for (int n = 0; n < 4; ++n) acc[m][n] = (f32x4){0.f, 0.f, 0.f, 0.f};
  int wm = wid >> 1, wn = wid & 1;
#pragma unroll 1
  for (int kt = 0; kt < FF / 64; ++kt) {
    size_t ko = (size_t)kt * 128;
#pragma unroll
    for (int j = 0; j < 4; ++j) {
      async_copy16(ag[j] + ko, la[j]);
      async_copy16(bg[j] + ko, lb[j]);
    }
    __syncthreads();
#pragma unroll
    for (int kk = 0; kk < 2; ++kk) {
      bf16x8 a[4], b[4];
#pragma unroll
      for (int m = 0; m < 4; ++m)
        a[m] = *(const bf16x8*)&As[(wm * 64 + m * 16 + (lane & 15)) * 64 + kk * 32 + (lane >> 4) * 8];
#pragma unroll
      for (int n = 0; n < 4; ++n)
        b[n] = *(const bf16x8*)&Bs[(wn * 64 + n * 16 + (lane & 15)) * 64 + kk * 32 + (lane >> 4) * 8];
#pragma unroll
      for (int m = 0; m < 4; ++m)
#pragma unroll
        for (int n = 0; n < 4; ++n)
          acc[m][n] = __builtin_amdgcn_mfma_f32_16x16x32_bf16(a[m], b[n], acc[m][n], 0, 0, 0);
    }
    __syncthreads();
  }
  int lc = lane & 15, lr = (lane >> 4) * 4;
#pragma unroll
  for (int m = 0; m < 4; ++m) {
#pragma unroll
    for (int n = 0; n < 4; ++n) {
      int col = nt * 128 + wn * 64 + n * 16 + lc;
#pragma unroll
      for (int i = 0; i < 4; ++i) {
        int trow = wm * 64 + m * 16 + lr + i;
        if (mt * 128 + trow < ce) {
          out[(size_t)toks[trow] * DIM + col] = wsc[trow] * acc[m][n][i];
        }
      }
    }
  }
}

extern "C" void kernel_launch(void* const* d_in, const int* in_sizes, int n_in,
                              void* d_out, int out_size, void* d_ws, size_t ws_size,
                              hipStream_t stream) {
  (void)in_sizes; (void)n_in; (void)out_size; (void)ws_size;
  const float* x  = (const float*)d_in[0];
  const float* Wg = (const float*)d_in[1];
  const float* W1 = (const float*)d_in[2];
  const float* W2 = (const float*)d_in[3];
  float* out = (float*)d_out;

  char* ws = (char*)d_ws;
  size_t off = 0;
  auto alloc = [&](size_t bytes) -> void* {
    void* p = ws + off;
    off += (bytes + 255) & ~(size_t)255;
    return p;
  };
  u16* xb   = (u16*)alloc((size_t)T_TOK * DIM * 2);   // 32 MB
  u16* w1t  = (u16*)alloc((size_t)NE * FF * DIM * 2); // 32 MB  [E][F][D]
  u16* w2t  = (u16*)alloc((size_t)NE * DIM * FF * 2); // 32 MB  [E][D][F]
  u16* H    = (u16*)alloc((size_t)T_TOK * FF * 2);    // 64 MB
  float* probs = (float*)alloc((size_t)T_TOK * NE * 4);
  unsigned char* sel = (unsigned char*)alloc((size_t)NE * T_TOK);
  float* wgt   = (float*)alloc((size_t)T_TOK * 4);
  int* tok2exp = (int*)alloc((size_t)T_TOK * 4);
  int* list    = (int*)alloc((size_t)T_TOK * 4);
  int* cnt     = (int*)alloc(64);
  int* cnt2    = (int*)alloc(64);
  int* basep   = (int*)alloc(64);

  // weight convert+transpose to bf16 B^T layouts
  transpose_cvt<<<dim3(FF / 32, DIM / 32, NE), dim3(32, 8), 0, stream>>>(W1, w1t, DIM, FF);
  transpose_cvt<<<dim3(DIM / 32, FF / 32, NE), dim3(32, 8), 0, stream>>>(W2, w2t, FF, DIM);
  // router (fp64-accurate logits) + x->bf16
  router_k<<<T_TOK / 4, 256, 0, stream>>>(x, Wg, probs, xb);
  // exact per-expert top-cap selection
  topk_sel<<<NE, 256, 0, stream>>>(probs, sel);
  // conflict resolution + compaction
  init_k<<<1, 64, 0, stream>>>(cnt, cnt2);
  assign_k<<<T_TOK / 256, 256, 0, stream>>>(probs, sel, tok2exp, wgt, cnt);
  prefix_k<<<1, 64, 0, stream>>>(cnt, basep);
  slot_k<<<T_TOK / 256, 256, 0, stream>>>(tok2exp, basep, cnt2, list);
  // expert FFN (grouped bf16 MFMA GEMMs)
  ffn1_k<<<dim3(FF / 128, T_TOK / 128, NE), 256, 0, stream>>>(xb, w1t, H, list, basep, cnt);
  ffn2_k<<<dim3(DIM / 128, T_TOK / 128, NE), 256, 0, stream>>>(H, w2t, out, list, wgt, basep, cnt);
}

// Round 2
// 557.030 us; speedup vs baseline: 1.0386x; 1.0386x over previous
//
#include <hip/hip_runtime.h>
#include <hip/hip_bf16.h>
#include <math.h>

// ExpertChoiceMoELayer: B=8,S=2048,D=1024,F=2048,E=8 -> T=16384, cap=2048
#define T_TOK 16384
#define DIM   1024
#define FF    2048
#define NE    8
#define CAPK  2048

typedef unsigned short u16;
typedef __attribute__((ext_vector_type(8))) short bf16x8;
typedef __attribute__((ext_vector_type(4))) float f32x4;

__device__ __forceinline__ u16 f2bf(float f) {
  __hip_bfloat16 h = __float2bfloat16(f);
  union { __hip_bfloat16 h; u16 u; } c; c.h = h; return c.u;
}

__device__ __forceinline__ void async_copy16(const void* g, void* l) {
  __builtin_amdgcn_global_load_lds(
      (const __attribute__((address_space(1))) unsigned int*)g,
      (__attribute__((address_space(3))) unsigned int*)l, 16, 0, 0);
}

// ---- fp32 [E][R][C] -> bf16 [E][C][R] (B^T layout for MFMA GEMMs) ----
__global__ __launch_bounds__(256) void transpose_cvt(const float* __restrict__ src,
                                                     u16* __restrict__ dst, int R, int C) {
  __shared__ float tile[32][33];
  int e = blockIdx.z;
  int c0 = blockIdx.x * 32, r0 = blockIdx.y * 32;
  const float* s = src + (size_t)e * R * C;
  u16* d = dst + (size_t)e * R * C;
  int tx = threadIdx.x, ty = threadIdx.y; // 32 x 8
#pragma unroll
  for (int i = 0; i < 4; ++i) {
    int r = r0 + ty + i * 8;
    tile[ty + i * 8][tx] = s[(size_t)r * C + c0 + tx];
  }
  __syncthreads();
#pragma unroll
  for (int i = 0; i < 4; ++i) {
    int c = c0 + ty + i * 8;
    d[(size_t)c * R + r0 + tx] = f2bf(tile[tx][ty + i * 8]);
  }
}

// ---- router: logits (fp64 accum) + softmax; also emits xb (bf16 copy of x) ----
__global__ __launch_bounds__(256) void router_k(const float* __restrict__ x,
                                                const float* __restrict__ Wg,
                                                float* __restrict__ probs,
                                                u16* __restrict__ xb) {
  __shared__ float wg_s[DIM * NE]; // 32 KB
  int tid = threadIdx.x;
  for (int i = tid; i < DIM * NE; i += 256) wg_s[i] = Wg[i];
  __syncthreads();
  int wid = tid >> 6, lane = tid & 63;
  int t = blockIdx.x * 4 + wid;
  const float* xr = x + (size_t)t * DIM;
  u16* xbr = xb + (size_t)t * DIM;
  double acc[NE] = {0, 0, 0, 0, 0, 0, 0, 0};
#pragma unroll 1
  for (int it = 0; it < DIM / 64; ++it) {
    int d = it * 64 + lane;
    float xv = xr[d];
    xbr[d] = f2bf(xv);
    const float4* wrow = (const float4*)&wg_s[d * NE];
    float4 w0 = wrow[0], w1 = wrow[1];
    acc[0] += (double)xv * (double)w0.x;
    acc[1] += (double)xv * (double)w0.y;
    acc[2] += (double)xv * (double)w0.z;
    acc[3] += (double)xv * (double)w0.w;
    acc[4] += (double)xv * (double)w1.x;
    acc[5] += (double)xv * (double)w1.y;
    acc[6] += (double)xv * (double)w1.z;
    acc[7] += (double)xv * (double)w1.w;
  }
#pragma unroll
  for (int e = 0; e < NE; ++e)
    for (int o = 32; o > 0; o >>= 1) acc[e] += __shfl_down(acc[e], o, 64);
  if (lane == 0) {
    float l[NE], mx = -3.0e38f;
#pragma unroll
    for (int e = 0; e < NE; ++e) { l[e] = (float)acc[e]; mx = fmaxf(mx, l[e]); }
    float s = 0.f;
#pragma unroll
    for (int e = 0; e < NE; ++e) { l[e] = expf(l[e] - mx); s += l[e]; }
    float inv = 1.0f / s;
#pragma unroll
    for (int e = 0; e < NE; ++e) probs[(size_t)t * NE + e] = l[e] * inv;
  }
}

// ---- per-expert exact top-CAPK selection (LDS-staged radix select) ----
__global__ __launch_bounds__(256) void topk_sel(const float* __restrict__ probs,
                                                unsigned char* __restrict__ sel) {
  __shared__ float pcol[T_TOK];      // 64 KB
  __shared__ unsigned int hist[256];
  __shared__ unsigned int bcast[2];
  __shared__ int tcnt[256];
  int e = blockIdx.x, tid = threadIdx.x;
  for (int i = tid; i < T_TOK; i += 256) pcol[i] = probs[(size_t)i * NE + e];
  __syncthreads();
  unsigned prefix = 0, remaining = CAPK;
#pragma unroll 1
  for (int level = 0; level < 4; ++level) {
    int shift = 24 - 8 * level;
    hist[tid] = 0;
    __syncthreads();
    for (int i = tid; i < T_TOK; i += 256) {
      unsigned k = __float_as_uint(pcol[i]);
      if (level == 0 || (k >> (shift + 8)) == prefix)
        atomicAdd(&hist[(k >> shift) & 255u], 1u);
    }
    __syncthreads();
    if (tid == 0) {
      unsigned cum = 0;
      for (int b = 255; b >= 0; --b) {
        cum += hist[b];
        if (cum >= remaining) {
          bcast[0] = (unsigned)b;
          bcast[1] = remaining - (cum - hist[b]);
          break;
        }
      }
    }
    __syncthreads();
    prefix = (prefix << 8) | bcast[0];
    remaining = bcast[1];
    __syncthreads();
  }
  unsigned vk = prefix;
  int need = (int)remaining;
  const int CH = T_TOK / 256; // 64 tokens per thread, contiguous
  int i0 = tid * CH;
  int myt = 0;
  for (int i = i0; i < i0 + CH; ++i)
    myt += (__float_as_uint(pcol[i]) == vk);
  tcnt[tid] = myt;
  __syncthreads();
  if (tid == 0) {
    int r = 0;
    for (int j = 0; j < 256; ++j) { int v = tcnt[j]; tcnt[j] = r; r += v; }
  }
  __syncthreads();
  int run = tcnt[tid];
  for (int i = i0; i < i0 + CH; ++i) {
    unsigned k = __float_as_uint(pcol[i]);
    unsigned char s = 0;
    if (k > vk) s = 1;
    else if (k == vk) { if (run < need) s = 1; run++; }
    sel[(size_t)e * T_TOK + i] = s;
  }
}

__global__ void init_k(int* cnt, int* cnt2) {
  int i = threadIdx.x;
  if (i < NE) { cnt[i] = 0; cnt2[i] = 0; }
}

__global__ __launch_bounds__(256) void assign_k(const float* __restrict__ probs,
                                                const unsigned char* __restrict__ sel,
                                                int* __restrict__ tok2exp,
                                                float* __restrict__ wgt, int* cnt) {
  int t = blockIdx.x * 256 + threadIdx.x;
  float p[NE];
#pragma unroll
  for (int e = 0; e < NE; ++e) p[e] = probs[(size_t)t * NE + e];
  int best = -1; float bp = -3.0e38f;
#pragma unroll
  for (int e = 0; e < NE; ++e)
    if (sel[(size_t)e * T_TOK + t] && p[e] > bp) { bp = p[e]; best = e; }
  if (best < 0) {
#pragma unroll
    for (int e = 0; e < NE; ++e)
      if (p[e] > bp) { bp = p[e]; best = e; }
  }
  tok2exp[t] = best;
  wgt[t] = bp;
  atomicAdd(&cnt[best], 1);
}

__global__ void prefix_k(const int* cnt, int* basep) {
  if (threadIdx.x == 0) {
    int r = 0;
    for (int e = 0; e < NE; ++e) { basep[e] = r; r += cnt[e]; }
  }
}

__global__ __launch_bounds__(256) void slot_k(const int* __restrict__ tok2exp,
                                              const int* __restrict__ basep,
                                              int* cnt2, int* __restrict__ list) {
  int t = blockIdx.x * 256 + threadIdx.x;
  int e = tok2exp[t];
  int s = basep[e] + atomicAdd(&cnt2[e], 1);
  list[s] = t;
}

// ============ pipelined grouped GEMM: 256x256 tile, BK=64 (2 k-halves), ============
// 4 phases/K-tile, counted vmcnt, swizzled LDS, setprio around MFMA clusters.
// EPI=0: H[slot] = GELU(xb[tok] @ W1t^T)   (K=DIM, N=FF)
// EPI=1: out[tok] = wgt * (H[slot] @ W2t^T) (K=FF,  N=DIM)

#define MF(M, N_, AV, BV) acc[M][N_] = __builtin_amdgcn_mfma_f32_16x16x32_bf16(AV, BV, acc[M][N_], 0, 0, 0)

#define PHASE_DSA(db, kk, mh)                                                     \
  pa = sm + (((db) * 4 + (kk)) * 16384) + wr * 8192 + (mh) * 4096 + laneOff;      \
  a0 = *(const bf16x8*)(pa);                                                      \
  a1 = *(const bf16x8*)(pa + 1024);                                               \
  a2 = *(const bf16x8*)(pa + 2048);                                               \
  a3 = *(const bf16x8*)(pa + 3072);

#define PHASE_DSB(db, kk)                                                         \
  pb = sm + (((db) * 4 + 2 + (kk)) * 16384) + wc * 4096 + laneOff;                \
  b0 = *(const bf16x8*)(pb);                                                      \
  b1 = *(const bf16x8*)(pb + 1024);                                               \
  b2 = *(const bf16x8*)(pb + 2048);                                               \
  b3 = *(const bf16x8*)(pb + 3072);

#define PHASE_MFMA(mh)                                                            \
  do {                                                                            \
    __builtin_amdgcn_s_setprio(1);                                                \
    MF((mh) * 4 + 0, 0, a0, b0); MF((mh) * 4 + 0, 1, a0, b1);                     \
    MF((mh) * 4 + 0, 2, a0, b2); MF((mh) * 4 + 0, 3, a0, b3);                     \
    MF((mh) * 4 + 1, 0, a1, b0); MF((mh) * 4 + 1, 1, a1, b1);                     \
    MF((mh) * 4 + 1, 2, a1, b2); MF((mh) * 4 + 1, 3, a1, b3);                     \
    MF((mh) * 4 + 2, 0, a2, b0); MF((mh) * 4 + 2, 1, a2, b1);                     \
    MF((mh) * 4 + 2, 2, a2, b2); MF((mh) * 4 + 2, 3, a2, b3);                     \
    MF((mh) * 4 + 3, 0, a3, b0); MF((mh) * 4 + 3, 1, a3, b1);                     \
    MF((mh) * 4 + 3, 2, a3, b2); MF((mh) * 4 + 3, 3, a3, b3);                     \
    __builtin_amdgcn_s_setprio(0);                                                \
  } while (0)

#define STAGE_A(db, kh, kt)                                                        \
  do {                                                                             \
    async_copy16(aP0 + (kt) * 128 + (kh) * 64,                                     \
                 sm + (((db) * 4 + (kh)) * 16384) + wid * 1024);                   \
    async_copy16(aP1 + (kt) * 128 + (kh) * 64,                                     \
                 sm + (((db) * 4 + (kh)) * 16384) + 8192 + wid * 1024);            \
  } while (0)

#define STAGE_B(db, kh, kt)                                                        \
  do {                                                                             \
    async_copy16(bP0 + (kt) * 128 + (kh) * 64,                                     \
                 sm + (((db) * 4 + 2 + (kh)) * 16384) + wid * 1024);               \
    async_copy16(bP1 + (kt) * 128 + (kh) * 64,                                     \
                 sm + (((db) * 4 + 2 + (kh)) * 16384) + 8192 + wid * 1024);        \
  } while (0)

#define BAR() asm volatile("s_barrier" ::: "memory")
#define VM4_BAR() asm volatile("s_waitcnt vmcnt(4)\n\ts_barrier" ::: "memory")
#define VM0_BAR() asm volatile("s_waitcnt vmcnt(0)\n\ts_barrier" ::: "memory")

template <int EPI>
__global__ __launch_bounds__(512, 2) void ffn_k(const u16* __restrict__ A,
                                                const u16* __restrict__ Bm,
                                                void* __restrict__ Out,
                                                const int* __restrict__ list,
                                                const float* __restrict__ wgt,
                                                const int* __restrict__ basep,
                                                const int* __restrict__ cnt) {
  constexpr int K = EPI ? FF : DIM;
  constexpr int N = EPI ? DIM : FF;
  constexpr int KT = K / 64;

  const int e = blockIdx.z, mt = blockIdx.y, nt = blockIdx.x;
  const int ce = cnt[e];
  if (mt * 256 >= ce) return;
  const int be = basep[e];

  __shared__ u16 smem[65536];   // 128 KiB: [dbuf2][A/B][khalf2][16KB region]
  __shared__ int toks[256];
  __shared__ float wsc[256];
  char* const sm = (char*)smem;

  const int tid = threadIdx.x;
  if (tid < 256) {
    int r = mt * 256 + tid;
    int tk = (r < ce) ? list[be + r] : list[be];
    toks[tid] = tk;
    wsc[tid] = wgt[tk];
  }
  __syncthreads();

  const int wid = tid >> 6, lane = tid & 63;
  const int wr = wid >> 2, wc = wid & 3;
  // swizzled per-lane frag-read offset within a 16KB k-half region:
  // tile row r at byte cb: phys = (r>>1)*128 + (r&1)*64 + (cb ^ (((r>>1)&3)<<4))
  const int laneOff = ((lane & 15) >> 1) * 128 + (lane & 1) * 64 +
                      (((lane >> 4) << 4) ^ (((lane >> 1) & 3) << 4));

  // stage source prep: thread tid covers tile rows tid/4 and 128+tid/4;
  // logical byte-in-64B-khalf-row = inverse swizzle of linear LDS slot
  const int tr0 = tid >> 2, tr1 = 128 + (tid >> 2);
  const int cbl = ((tid & 3) << 4) ^ ((tid & 24) << 1);
  const char *aP0, *aP1;
  if (EPI == 0) {
    aP0 = (const char*)(A + (size_t)toks[tr0] * K) + cbl;
    aP1 = (const char*)(A + (size_t)toks[tr1] * K) + cbl;
  } else {
    int g0 = mt * 256 + tr0; if (g0 >= ce) g0 = ce - 1;
    int g1 = mt * 256 + tr1; if (g1 >= ce) g1 = ce - 1;
    aP0 = (const char*)(A + ((size_t)be + g0) * K) + cbl;
    aP1 = (const char*)(A + ((size_t)be + g1) * K) + cbl;
  }
  const char* bP0 = (const char*)(Bm + ((size_t)e * N + nt * 256 + tr0) * K) + cbl;
  const char* bP1 = (const char*)(Bm + ((size_t)e * N + nt * 256 + tr1) * K) + cbl;

  f32x4 acc[8][4];
#pragma unroll
  for (int m = 0; m < 8; ++m)
#pragma unroll
    for (int n = 0; n < 4; ++n) acc[m][n] = (f32x4){0.f, 0.f, 0.f, 0.f};

  // prologue: stage tile 0 (order A-k0, B-k0, A-k1, B-k1), publish first halves
  STAGE_A(0, 0, 0);
  STAGE_B(0, 0, 0);
  STAGE_A(0, 1, 0);
  STAGE_B(0, 1, 0);
  VM4_BAR();

  const char* pa;
  const char* pb;
  bf16x8 a0, a1, a2, a3, b0, b1, b2, b3;

#pragma unroll 1
  for (int t = 0; t < KT - 1; ++t) {
    const int db = t & 1, dn = db ^ 1, kn = t + 1;
    // P1: quadrant (mh0, kk0); prefetch A-k0 of tile t+1
    PHASE_DSA(db, 0, 0);
    PHASE_DSB(db, 0);
    STAGE_A(dn, 0, kn);
    BAR();
    PHASE_MFMA(0);
    // P2: (mh1, kk0); prefetch B-k0; publish this tile's k1 halves
    PHASE_DSA(db, 0, 1);
    STAGE_B(dn, 0, kn);
    VM4_BAR();
    PHASE_MFMA(1);
    // P3: (mh0, kk1); prefetch A-k1
    PHASE_DSA(db, 1, 0);
    PHASE_DSB(db, 1);
    STAGE_A(dn, 1, kn);
    BAR();
    PHASE_MFMA(0);
    // P4: (mh1, kk1); prefetch B-k1; publish next tile's k0 halves
    PHASE_DSA(db, 1, 1);
    STAGE_B(dn, 1, kn);
    VM4_BAR();
    PHASE_MFMA(1);
  }
  { // last tile (no prefetch; drain remaining k1 halves at P2)
    const int db = (KT - 1) & 1;
    PHASE_DSA(db, 0, 0);
    PHASE_DSB(db, 0);
    BAR();
    PHASE_MFMA(0);
    PHASE_DSA(db, 0, 1);
    VM0_BAR();
    PHASE_MFMA(1);
    PHASE_DSA(db, 1, 0);
    PHASE_DSB(db, 1);
    BAR();
    PHASE_MFMA(0);
    PHASE_DSA(db, 1, 1);
    PHASE_MFMA(1);
  }

  // epilogue
  const int lc = lane & 15, lr = (lane >> 4) * 4;
#pragma unroll
  for (int m = 0; m < 8; ++m) {
#pragma unroll
    for (int n = 0; n < 4; ++n) {
      int col = nt * 256 + wc * 64 + n * 16 + lc;
#pragma unroll
      for (int i = 0; i < 4; ++i) {
        int trow = wr * 128 + m * 16 + lr + i;
        int grow = mt * 256 + trow;
        if (grow < ce) {
          float v = acc[m][n][i];
          if (EPI == 0) {
            float g = 0.5f * v * (1.0f + erff(v * 0.70710678118654752f));
            ((u16*)Out)[(size_t)(be + grow) * FF + col] = f2bf(g);
          } else {
            ((float*)Out)[(size_t)toks[trow] * DIM + col] = wsc[trow] * v;
          }
        }
      }
    }
  }
}

extern "C" void kernel_launch(void* const* d_in, const int* in_sizes, int n_in,
                              void* d_out, int out_size, void* d_ws, size_t ws_size,
                              hipStream_t stream) {
  (void)in_sizes; (void)n_in; (void)out_size; (void)ws_size;
  const float* x  = (const float*)d_in[0];
  const float* Wg = (const float*)d_in[1];
  const float* W1 = (const float*)d_in[2];
  const float* W2 = (const float*)d_in[3];
  float* out = (float*)d_out;

  char* ws = (char*)d_ws;
  size_t off = 0;
  auto alloc = [&](size_t bytes) -> void* {
    void* p = ws + off;
    off += (bytes + 255) & ~(size_t)255;
    return p;
  };
  u16* xb   = (u16*)alloc((size_t)T_TOK * DIM * 2);   // 32 MB
  u16* w1t  = (u16*)alloc((size_t)NE * FF * DIM * 2); // 32 MB  [E][F][D]
  u16* w2t  = (u16*)alloc((size_t)NE * DIM * FF * 2); // 32 MB  [E][D][F]
  u16* H    = (u16*)alloc((size_t)T_TOK * FF * 2);    // 64 MB
  float* probs = (float*)alloc((size_t)T_TOK * NE * 4);
  unsigned char* sel = (unsigned char*)alloc((size_t)NE * T_TOK);
  float* wgt   = (float*)alloc((size_t)T_TOK * 4);
  int* tok2exp = (int*)alloc((size_t)T_TOK * 4);
  int* list    = (int*)alloc((size_t)T_TOK * 4);
  int* cnt     = (int*)alloc(64);
  int* cnt2    = (int*)alloc(64);
  int* basep   = (int*)alloc(64);

  transpose_cvt<<<dim3(FF / 32, DIM / 32, NE), dim3(32, 8), 0, stream>>>(W1, w1t, DIM, FF);
  transpose_cvt<<<dim3(DIM / 32, FF / 32, NE), dim3(32, 8), 0, stream>>>(W2, w2t, FF, DIM);
  router_k<<<T_TOK / 4, 256, 0, stream>>>(x, Wg, probs, xb);
  topk_sel<<<NE, 256, 0, stream>>>(probs, sel);
  init_k<<<1, 64, 0, stream>>>(cnt, cnt2);
  assign_k<<<T_TOK / 256, 256, 0, stream>>>(probs, sel, tok2exp, wgt, cnt);
  prefix_k<<<1, 64, 0, stream>>>(cnt, basep);
  slot_k<<<T_TOK / 256, 256, 0, stream>>>(tok2exp, basep, cnt2, list);
  ffn_k<0><<<dim3(FF / 256, 64, NE), 512, 0, stream>>>(xb, w1t, H, list, wgt, basep, cnt);
  ffn_k<1><<<dim3(DIM / 256, 64, NE), 512, 0, stream>>>(H, w2t, out, list, wgt, basep, cnt);
}

// Round 3
// 501.776 us; speedup vs baseline: 1.1529x; 1.1101x over previous
//
#include <hip/hip_runtime.h>
#include <hip/hip_bf16.h>
#include <math.h>

// ExpertChoiceMoELayer: B=8,S=2048,D=1024,F=2048,E=8 -> T=16384, cap=2048
#define T_TOK 16384
#define DIM   1024
#define FF    2048
#define NE    8
#define CAPK  2048
#define WLMAX 80

typedef unsigned short u16;
typedef __attribute__((ext_vector_type(8))) short bf16x8;
typedef __attribute__((ext_vector_type(4))) float f32x4;

__device__ __forceinline__ u16 f2bf(float f) {
  __hip_bfloat16 h = __float2bfloat16(f);
  union { __hip_bfloat16 h; u16 u; } c; c.h = h; return c.u;
}

// fast GELU: 0.5x(1+erf(x/sqrt2)), erf via Abramowitz-Stegun 7.1.26 (|err|<=1.5e-7)
__device__ __forceinline__ float gelu_f(float v) {
  float z = fabsf(v) * 0.70710678118654752f;
  float t = __builtin_amdgcn_rcpf(1.0f + 0.3275911f * z);
  float poly = t * (0.254829592f +
               t * (-0.284496736f +
               t * (1.421413741f +
               t * (-1.453152027f +
               t * 1.061405429f))));
  float ez = __expf(-z * z);
  float erfz = 1.0f - poly * ez;
  erfz = copysignf(erfz, v);
  return 0.5f * v * (1.0f + erfz);
}

__device__ __forceinline__ void async_copy16(const void* g, void* l) {
  __builtin_amdgcn_global_load_lds(
      (const __attribute__((address_space(1))) unsigned int*)g,
      (__attribute__((address_space(3))) unsigned int*)l, 16, 0, 0);
}

// ---- fp32 [E][R][C] -> bf16 [E][C][R] (B^T layout for MFMA GEMMs) ----
__global__ __launch_bounds__(256) void transpose_cvt(const float* __restrict__ src,
                                                     u16* __restrict__ dst, int R, int C) {
  __shared__ float tile[32][33];
  int e = blockIdx.z;
  int c0 = blockIdx.x * 32, r0 = blockIdx.y * 32;
  const float* s = src + (size_t)e * R * C;
  u16* d = dst + (size_t)e * R * C;
  int tx = threadIdx.x, ty = threadIdx.y; // 32 x 8
#pragma unroll
  for (int i = 0; i < 4; ++i) {
    int r = r0 + ty + i * 8;
    tile[ty + i * 8][tx] = s[(size_t)r * C + c0 + tx];
  }
  __syncthreads();
#pragma unroll
  for (int i = 0; i < 4; ++i) {
    int c = c0 + ty + i * 8;
    d[(size_t)c * R + r0 + tx] = f2bf(tile[tx][ty + i * 8]);
  }
}

// ---- router: logits (fp64 accum) + softmax; also emits xb (bf16 copy of x) ----
__global__ __launch_bounds__(256) void router_k(const float* __restrict__ x,
                                                const float* __restrict__ Wg,
                                                float* __restrict__ probs,
                                                u16* __restrict__ xb) {
  int tid = threadIdx.x;
  int wid = tid >> 6, lane = tid & 63;
  int t = blockIdx.x * 4 + wid;
  const float* xr = x + (size_t)t * DIM;
  u16* xbr = xb + (size_t)t * DIM;
  double acc[NE] = {0, 0, 0, 0, 0, 0, 0, 0};
#pragma unroll 1
  for (int it = 0; it < DIM / 64; ++it) {
    int d = it * 64 + lane;
    float xv = xr[d];
    xbr[d] = f2bf(xv);
    const float4* wrow = (const float4*)(Wg + (size_t)d * NE); // L1/L2-resident (32 KB)
    float4 w0 = wrow[0], w1 = wrow[1];
    acc[0] += (double)xv * (double)w0.x;
    acc[1] += (double)xv * (double)w0.y;
    acc[2] += (double)xv * (double)w0.z;
    acc[3] += (double)xv * (double)w0.w;
    acc[4] += (double)xv * (double)w1.x;
    acc[5] += (double)xv * (double)w1.y;
    acc[6] += (double)xv * (double)w1.z;
    acc[7] += (double)xv * (double)w1.w;
  }
#pragma unroll
  for (int e = 0; e < NE; ++e)
    for (int o = 32; o > 0; o >>= 1) acc[e] += __shfl_down(acc[e], o, 64);
  if (lane == 0) {
    float l[NE], mx = -3.0e38f;
#pragma unroll
    for (int e = 0; e < NE; ++e) { l[e] = (float)acc[e]; mx = fmaxf(mx, l[e]); }
    float s = 0.f;
#pragma unroll
    for (int e = 0; e < NE; ++e) { l[e] = expf(l[e] - mx); s += l[e]; }
    float inv = 1.0f / s;
#pragma unroll
    for (int e = 0; e < NE; ++e) probs[(size_t)t * NE + e] = l[e] * inv;
  }
}

// ---- per-expert exact top-CAPK selection: 3-level radix (11/11/10 bits) ----
__global__ __launch_bounds__(256) void topk_sel(const float* __restrict__ probs,
                                                unsigned char* __restrict__ sel) {
  __shared__ float pcol[T_TOK];        // 64 KB
  __shared__ unsigned int hist[2048];  // 8 KB
  __shared__ unsigned int chunk[256];
  __shared__ unsigned int bcast[2];
  __shared__ int tcnt[256];
  int e = blockIdx.x, tid = threadIdx.x;
  for (int i = tid; i < T_TOK; i += 256) pcol[i] = probs[(size_t)i * NE + e];
  unsigned prefix = 0, remaining = CAPK;
#pragma unroll 1
  for (int lvl = 0; lvl < 3; ++lvl) {
    int nb = (lvl == 2) ? 1024 : 2048;
    for (int i = tid; i < 2048; i += 256) hist[i] = 0;
    __syncthreads();
    for (int i = tid; i < T_TOK; i += 256) {
      unsigned k = __float_as_uint(pcol[i]);
      bool m = (lvl == 0) || (lvl == 1 && (k >> 21) == prefix) ||
               (lvl == 2 && (k >> 10) == prefix);
      if (m) {
        unsigned b = (lvl == 0) ? (k >> 21) : (lvl == 1) ? ((k >> 10) & 2047u) : (k & 1023u);
        atomicAdd(&hist[b], 1u);
      }
    }
    __syncthreads();
    int nper = nb / 256;
    unsigned s = 0;
    for (int j = nper - 1; j >= 0; --j) s += hist[tid * nper + j];
    chunk[tid] = s;
    __syncthreads();
    if (tid == 0) {
      unsigned cum = 0;
      int ct = 0;
      for (int t2 = 255; t2 >= 0; --t2) {
        if (cum + chunk[t2] >= remaining) { ct = t2; break; }
        cum += chunk[t2];
      }
      unsigned rem2 = remaining - cum, cum2 = 0;
      for (int j = nper - 1; j >= 0; --j) {
        unsigned h = hist[ct * nper + j];
        if (cum2 + h >= rem2) {
          bcast[0] = (unsigned)(ct * nper + j);
          bcast[1] = rem2 - cum2;
          break;
        }
        cum2 += h;
      }
    }
    __syncthreads();
    unsigned b = bcast[0];
    remaining = bcast[1];
    prefix = (lvl == 0) ? b : (lvl == 1) ? ((prefix << 11) | b) : ((prefix << 10) | b);
    __syncthreads();
  }
  unsigned vk = prefix;
  int need = (int)remaining;
  const int CH = T_TOK / 256; // 64 contiguous tokens per thread
  int i0 = tid * CH;
  int myt = 0;
  for (int i = i0; i < i0 + CH; ++i)
    myt += (__float_as_uint(pcol[i]) == vk);
  tcnt[tid] = myt;
  __syncthreads();
  if (tid == 0) {
    int r = 0;
    for (int j = 0; j < 256; ++j) { int v = tcnt[j]; tcnt[j] = r; r += v; }
  }
  __syncthreads();
  int run = tcnt[tid];
  for (int i = i0; i < i0 + CH; ++i) {
    unsigned k = __float_as_uint(pcol[i]);
    unsigned char sv = 0;
    if (k > vk) sv = 1;
    else if (k == vk) { if (run < need) sv = 1; run++; }
    sel[(size_t)e * T_TOK + i] = sv;
  }
}

__global__ void init_k(int* cnt, int* cnt2) {
  int i = threadIdx.x;
  if (i < NE) { cnt[i] = 0; cnt2[i] = 0; }
}

__global__ __launch_bounds__(256) void assign_k(const float* __restrict__ probs,
                                                const unsigned char* __restrict__ sel,
                                                int* __restrict__ tok2exp,
                                                float* __restrict__ wgt, int* cnt) {
  int t = blockIdx.x * 256 + threadIdx.x;
  float p[NE];
#pragma unroll
  for (int e = 0; e < NE; ++e) p[e] = probs[(size_t)t * NE + e];
  int best = -1; float bp = -3.0e38f;
#pragma unroll
  for (int e = 0; e < NE; ++e)
    if (sel[(size_t)e * T_TOK + t] && p[e] > bp) { bp = p[e]; best = e; }
  if (best < 0) {
#pragma unroll
    for (int e = 0; e < NE; ++e)
      if (p[e] > bp) { bp = p[e]; best = e; }
  }
  tok2exp[t] = best;
  wgt[t] = bp;
  atomicAdd(&cnt[best], 1);
}

// basep + flat (e,mt) worklist
__global__ void prefix_k(const int* cnt, int* basep, int* wl) {
  if (threadIdx.x == 0) {
    int r = 0, nw = 0;
    for (int e = 0; e < NE; ++e) {
      basep[e] = r;
      int nb = (cnt[e] + 255) >> 8;
      for (int b = 0; b < nb; ++b) { wl[2 * nw] = e; wl[2 * nw + 1] = b; nw++; }
      r += cnt[e];
    }
    for (int i = nw; i < WLMAX; ++i) { wl[2 * i] = -1; wl[2 * i + 1] = 0; }
  }
}

__global__ __launch_bounds__(256) void slot_k(const int* __restrict__ tok2exp,
                                              const int* __restrict__ basep,
                                              int* cnt2, int* __restrict__ list) {
  int t = blockIdx.x * 256 + threadIdx.x;
  int e = tok2exp[t];
  int s = basep[e] + atomicAdd(&cnt2[e], 1);
  list[s] = t;
}

// ============ pipelined grouped GEMM: 256x256 tile, BK=64 (2 k-halves), ============
// worklist grid, counted vmcnt, swizzled LDS, setprio, operand-swapped MFMA
// EPI=0: H[slot] = GELU(xb[tok] @ W1t^T)   (K=DIM, N=FF)
// EPI=1: out[tok] = wgt * (H[slot] @ W2t^T) (K=FF,  N=DIM)

// operand-swapped: rows<-b (N dim), cols<-a (M dim); C idx runs along output col
#define MF(M, N_, AV, BV) acc[M][N_] = __builtin_amdgcn_mfma_f32_16x16x32_bf16(BV, AV, acc[M][N_], 0, 0, 0)

#define PHASE_DSA(db, kk, mh)                                                     \
  pa = sm + (((db) * 4 + (kk)) * 16384) + wr * 8192 + (mh) * 4096 + laneOff;      \
  a0 = *(const bf16x8*)(pa);                                                      \
  a1 = *(const bf16x8*)(pa + 1024);                                               \
  a2 = *(const bf16x8*)(pa + 2048);                                               \
  a3 = *(const bf16x8*)(pa + 3072);

#define PHASE_DSB(db, kk)                                                         \
  pb = sm + (((db) * 4 + 2 + (kk)) * 16384) + wc * 4096 + laneOff;                \
  b0 = *(const bf16x8*)(pb);                                                      \
  b1 = *(const bf16x8*)(pb + 1024);                                               \
  b2 = *(const bf16x8*)(pb + 2048);                                               \
  b3 = *(const bf16x8*)(pb + 3072);

#define PHASE_MFMA(mh)                                                            \
  do {                                                                            \
    __builtin_amdgcn_s_setprio(1);                                                \
    MF((mh) * 4 + 0, 0, a0, b0); MF((mh) * 4 + 0, 1, a0, b1);                     \
    MF((mh) * 4 + 0, 2, a0, b2); MF((mh) * 4 + 0, 3, a0, b3);                     \
    MF((mh) * 4 + 1, 0, a1, b0); MF((mh) * 4 + 1, 1, a1, b1);                     \
    MF((mh) * 4 + 1, 2, a1, b2); MF((mh) * 4 + 1, 3, a1, b3);                     \
    MF((mh) * 4 + 2, 0, a2, b0); MF((mh) * 4 + 2, 1, a2, b1);                     \
    MF((mh) * 4 + 2, 2, a2, b2); MF((mh) * 4 + 2, 3, a2, b3);                     \
    MF((mh) * 4 + 3, 0, a3, b0); MF((mh) * 4 + 3, 1, a3, b1);                     \
    MF((mh) * 4 + 3, 2, a3, b2); MF((mh) * 4 + 3, 3, a3, b3);                     \
    __builtin_amdgcn_s_setprio(0);                                                \
  } while (0)

#define STAGE_A(db, kh, kt)                                                        \
  do {                                                                             \
    async_copy16(aP0 + (kt) * 128 + (kh) * 64,                                     \
                 sm + (((db) * 4 + (kh)) * 16384) + wid * 1024);                   \
    async_copy16(aP1 + (kt) * 128 + (kh) * 64,                                     \
                 sm + (((db) * 4 + (kh)) * 16384) + 8192 + wid * 1024);            \
  } while (0)

#define STAGE_B(db, kh, kt)                                                        \
  do {                                                                             \
    async_copy16(bP0 + (kt) * 128 + (kh) * 64,                                     \
                 sm + (((db) * 4 + 2 + (kh)) * 16384) + wid * 1024);               \
    async_copy16(bP1 + (kt) * 128 + (kh) * 64,                                     \
                 sm + (((db) * 4 + 2 + (kh)) * 16384) + 8192 + wid * 1024);        \
  } while (0)

#define BAR() asm volatile("s_barrier" ::: "memory")
#define VM4_BAR() asm volatile("s_waitcnt vmcnt(4)\n\ts_barrier" ::: "memory")
#define VM0_BAR() asm volatile("s_waitcnt vmcnt(0)\n\ts_barrier" ::: "memory")

template <int EPI>
__global__ __launch_bounds__(512, 2) void ffn_k(const u16* __restrict__ A,
                                                const u16* __restrict__ Bm,
                                                void* __restrict__ Out,
                                                const int* __restrict__ list,
                                                const float* __restrict__ wgt,
                                                const int* __restrict__ basep,
                                                const int* __restrict__ cnt,
                                                const int* __restrict__ wl) {
  constexpr int K = EPI ? FF : DIM;
  constexpr int N = EPI ? DIM : FF;
  constexpr int KT = K / 64;

  const int wi = blockIdx.y;
  const int e = wl[2 * wi];
  if (e < 0) return;
  const int mt = wl[2 * wi + 1];
  const int nt = blockIdx.x;
  const int ce = cnt[e];
  const int be = basep[e];

  __shared__ u16 smem[65536];   // 128 KiB: [dbuf2][A/B][khalf2][16KB region]
  __shared__ int toks[256];
  __shared__ float wsc[256];
  char* const sm = (char*)smem;

  const int tid = threadIdx.x;
  if (tid < 256) {
    int r = mt * 256 + tid;
    int tk = (r < ce) ? list[be + r] : list[be];
    toks[tid] = tk;
    wsc[tid] = wgt[tk];
  }
  __syncthreads();

  const int wid = tid >> 6, lane = tid & 63;
  const int wr = wid >> 2, wc = wid & 3;
  // swizzled per-lane frag-read offset within a 16KB k-half region
  const int laneOff = ((lane & 15) >> 1) * 128 + (lane & 1) * 64 +
                      (((lane >> 4) << 4) ^ (((lane >> 1) & 3) << 4));

  const int tr0 = tid >> 2, tr1 = 128 + (tid >> 2);
  const int cbl = ((tid & 3) << 4) ^ ((tid & 24) << 1);
  const char *aP0, *aP1;
  if (EPI == 0) {
    aP0 = (const char*)(A + (size_t)toks[tr0] * K) + cbl;
    aP1 = (const char*)(A + (size_t)toks[tr1] * K) + cbl;
  } else {
    int g0 = mt * 256 + tr0; if (g0 >= ce) g0 = ce - 1;
    int g1 = mt * 256 + tr1; if (g1 >= ce) g1 = ce - 1;
    aP0 = (const char*)(A + ((size_t)be + g0) * K) + cbl;
    aP1 = (const char*)(A + ((size_t)be + g1) * K) + cbl;
  }
  const char* bP0 = (const char*)(Bm + ((size_t)e * N + nt * 256 + tr0) * K) + cbl;
  const char* bP1 = (const char*)(Bm + ((size_t)e * N + nt * 256 + tr1) * K) + cbl;

  f32x4 acc[8][4];
#pragma unroll
  for (int m = 0; m < 8; ++m)
#pragma unroll
    for (int n = 0; n < 4; ++n) acc[m][n] = (f32x4){0.f, 0.f, 0.f, 0.f};

  // prologue: stage tile 0; publish first k-halves
  STAGE_A(0, 0, 0);
  STAGE_B(0, 0, 0);
  STAGE_A(0, 1, 0);
  STAGE_B(0, 1, 0);
  VM4_BAR();

  const char* pa;
  const char* pb;
  bf16x8 a0, a1, a2, a3, b0, b1, b2, b3;

#pragma unroll 1
  for (int t = 0; t < KT - 1; ++t) {
    const int db = t & 1, dn = db ^ 1, kn = t + 1;
    PHASE_DSA(db, 0, 0);
    PHASE_DSB(db, 0);
    STAGE_A(dn, 0, kn);
    BAR();
    PHASE_MFMA(0);
    PHASE_DSA(db, 0, 1);
    STAGE_B(dn, 0, kn);
    VM4_BAR();
    PHASE_MFMA(1);
    PHASE_DSA(db, 1, 0);
    PHASE_DSB(db, 1);
    STAGE_A(dn, 1, kn);
    BAR();
    PHASE_MFMA(0);
    PHASE_DSA(db, 1, 1);
    STAGE_B(dn, 1, kn);
    VM4_BAR();
    PHASE_MFMA(1);
  }
  { // last tile
    const int db = (KT - 1) & 1;
    PHASE_DSA(db, 0, 0);
    PHASE_DSB(db, 0);
    BAR();
    PHASE_MFMA(0);
    PHASE_DSA(db, 0, 1);
    VM0_BAR();
    PHASE_MFMA(1);
    PHASE_DSA(db, 1, 0);
    PHASE_DSB(db, 1);
    BAR();
    PHASE_MFMA(0);
    PHASE_DSA(db, 1, 1);
    PHASE_MFMA(1);
  }

  // epilogue: operand-swap => reg index i runs along output cols -> vector stores
  const int lc = lane & 15, lq = (lane >> 4) * 4;
#pragma unroll
  for (int m = 0; m < 8; ++m) {
    int trow = wr * 128 + m * 16 + lc;
    int grow = mt * 256 + trow;
    if (grow < ce) {
      if (EPI == 0) {
        size_t rowoff = (size_t)(be + grow) * FF + nt * 256 + wc * 64 + lq;
#pragma unroll
        for (int n = 0; n < 4; ++n) {
          ushort4 h4;
          h4.x = f2bf(gelu_f(acc[m][n][0]));
          h4.y = f2bf(gelu_f(acc[m][n][1]));
          h4.z = f2bf(gelu_f(acc[m][n][2]));
          h4.w = f2bf(gelu_f(acc[m][n][3]));
          *(ushort4*)((u16*)Out + rowoff + n * 16) = h4;
        }
      } else {
        float w = wsc[trow];
        size_t rowoff = (size_t)toks[trow] * DIM + nt * 256 + wc * 64 + lq;
#pragma unroll
        for (int n = 0; n < 4; ++n) {
          float4 o = make_float4(w * acc[m][n][0], w * acc[m][n][1],
                                 w * acc[m][n][2], w * acc[m][n][3]);
          *(float4*)((float*)Out + rowoff + n * 16) = o;
        }
      }
    }
  }
}

extern "C" void kernel_launch(void* const* d_in, const int* in_sizes, int n_in,
                              void* d_out, int out_size, void* d_ws, size_t ws_size,
                              hipStream_t stream) {
  (void)in_sizes; (void)n_in; (void)out_size; (void)ws_size;
  const float* x  = (const float*)d_in[0];
  const float* Wg = (const float*)d_in[1];
  const float* W1 = (const float*)d_in[2];
  const float* W2 = (const float*)d_in[3];
  float* out = (float*)d_out;

  char* ws = (char*)d_ws;
  size_t off = 0;
  auto alloc = [&](size_t bytes) -> void* {
    void* p = ws + off;
    off += (bytes + 255) & ~(size_t)255;
    return p;
  };
  u16* xb   = (u16*)alloc((size_t)T_TOK * DIM * 2);   // 32 MB
  u16* w1t  = (u16*)alloc((size_t)NE * FF * DIM * 2); // 32 MB  [E][F][D]
  u16* w2t  = (u16*)alloc((size_t)NE * DIM * FF * 2); // 32 MB  [E][D][F]
  u16* H    = (u16*)alloc((size_t)T_TOK * FF * 2);    // 64 MB
  float* probs = (float*)alloc((size_t)T_TOK * NE * 4);
  unsigned char* sel = (unsigned char*)alloc((size_t)NE * T_TOK);
  float* wgt   = (float*)alloc((size_t)T_TOK * 4);
  int* tok2exp = (int*)alloc((size_t)T_TOK * 4);
  int* list    = (int*)alloc((size_t)T_TOK * 4);
  int* cnt     = (int*)alloc(64);
  int* cnt2    = (int*)alloc(64);
  int* basep   = (int*)alloc(64);
  int* wl      = (int*)alloc(WLMAX * 2 * 4);

  transpose_cvt<<<dim3(FF / 32, DIM / 32, NE), dim3(32, 8), 0, stream>>>(W1, w1t, DIM, FF);
  transpose_cvt<<<dim3(DIM / 32, FF / 32, NE), dim3(32, 8), 0, stream>>>(W2, w2t, FF, DIM);
  router_k<<<T_TOK / 4, 256, 0, stream>>>(x, Wg, probs, xb);
  topk_sel<<<NE, 256, 0, stream>>>(probs, sel);
  init_k<<<1, 64, 0, stream>>>(cnt, cnt2);
  assign_k<<<T_TOK / 256, 256, 0, stream>>>(probs, sel, tok2exp, wgt, cnt);
  prefix_k<<<1, 64, 0, stream>>>(cnt, basep, wl);
  slot_k<<<T_TOK / 256, 256, 0, stream>>>(tok2exp, basep, cnt2, list);
  ffn_k<0><<<dim3(FF / 256, WLMAX), 512, 0, stream>>>(xb, w1t, H, list, wgt, basep, cnt, wl);
  ffn_k<1><<<dim3(DIM / 256, WLMAX), 512, 0, stream>>>(H, w2t, out, list, wgt, basep, cnt, wl);
}